// Round 3
// baseline (124.820 us; speedup 1.0000x reference)
//
#include <hip/hip_runtime.h>
#include <math.h>

// MatchingLayer (BiMPM-style) — MI355X. Round 17: phase-2 LDS-issue halving,
// all-vector (NO readlane — round-15's poison):
//   * B panel staged jj-pair-interleaved (round-15's proven staging); phase-2
//     gathers one ds_read_b64 per TWO j's (64 -> 32 ops/wave),
//   * cos broadcast as float2 ds_read_b64 (64 -> 32 ops/wave),
//   * phase-cos B fragments from global chb/cpb (zero-padded K=128), scosC
//     masked to 0 for jj >= nv; cidx fully initialized,
//   * odd-nv tail separate (no zero product may enter the running max).
// Keepers: round-16 sam/sax/sl bank stagger; pair-path hoisted reciprocals.
// Grid (20+32, B) x 512 thr. B=32, L=128, H=100, P=20, C=105.

namespace {
constexpr int B = 32;
constexpr int L = 128;
constexpr int H = 100;
constexpr int P = 20;
constexpr int C = 105;
constexpr int TI = 8;            // i-rows per side tile
constexpr int SMEM_BYTES = 40768;
constexpr float EPSF = 1e-8f;
constexpr float MINV = -1e7f;
}

typedef unsigned short u16;
typedef unsigned int u32;
typedef short sh8 __attribute__((ext_vector_type(8)));   // 8 bf16 (4 VGPRs)
typedef float f4 __attribute__((ext_vector_type(4)));

__device__ __forceinline__ u16 f2bf(float f) {           // RNE f32->bf16
    u32 u = __float_as_uint(f);
    u += 0x7FFFu + ((u >> 16) & 1u);
    return (u16)(u >> 16);
}
__device__ __forceinline__ float bf2f(u32 h) {
    return __uint_as_float(h << 16);
}
__device__ __forceinline__ u32 pack2(float a, float b) {
    return (u32)f2bf(a) | ((u32)f2bf(b) << 16);
}
__device__ __forceinline__ sh8 zfrag() {
    return __builtin_bit_cast(sh8, (uint4){0u, 0u, 0u, 0u});
}

// ---------------------------------------------------------------- k_prep
// grid (L/8, B, 2), block 512. Block = 8 rows. Phase A: masked vector
// (fp32 + bf16 K=128 pad) + v^2 into LDS. Phase B: wave w = row w, 21 norm
// tasks x 3-lane K-split.
__global__ __launch_bounds__(512) void
k_prep(const float* __restrict__ ctx_p, const int* __restrict__ mask_p,
       const float* __restrict__ ctx_h, const int* __restrict__ mask_h,
       const float* __restrict__ w1,
       float* __restrict__ cp, float* __restrict__ ch,
       u16* __restrict__ cpb, u16* __restrict__ chb,
       float* __restrict__ np_, float* __restrict__ nh_,
       float* __restrict__ nwp, float* __restrict__ nwh)
{
    const int bx = blockIdx.x, b = blockIdx.y, side = blockIdx.z, t = threadIdx.x;
    const int i0 = bx * 8;
    const float* ctx = side ? ctx_h : ctx_p;
    const int*  mask = side ? mask_h : mask_p;
    float* dst  = side ? ch  : cp;
    u16*   dstb = side ? chb : cpb;
    float* nrm  = side ? nh_ : np_;
    float* nw   = side ? nwh : nwp;

    __shared__ __align__(16) float sv2[8][112];

    #pragma unroll
    for (int it = 0; it < 2; ++it) {
        int idx = it * 512 + t;
        int rr = idx >> 7, k = idx & 127;
        const int row = b * L + i0 + rr;
        const float m = (float)mask[row];
        float v = 0.f;
        if (k < H) {
            v = ctx[(size_t)row * H + k] * m;
            dst[(size_t)row * H + k] = v;
            sv2[rr][k] = v * v;
        }
        dstb[(size_t)row * 128 + k] = f2bf(v);
    }
    __syncthreads();

    const int wv = t >> 6, ln = t & 63;
    if (ln < 63) {
        const int g = ln / 3, seg = ln - 3 * g;
        const int k0 = (seg == 0) ? 0 : (seg == 1) ? 8 : 16;
        const int k1 = (seg == 0) ? 8 : (seg == 1) ? 16 : 25;
        const float4* v4 = (const float4*)sv2[wv];
        float acc = 0.f;
        if (g < P) {
            const float4* w4 = (const float4*)(w1 + g * H);
            for (int k = k0; k < k1; ++k) {
                float4 w = w4[k], s = v4[k];
                acc += w.x * w.x * s.x + w.y * w.y * s.y +
                       w.z * w.z * s.z + w.w * w.w * s.w;
            }
        } else {
            for (int k = k0; k < k1; ++k) {
                float4 s = v4[k];
                acc += s.x + s.y + s.z + s.w;
            }
        }
        float a1 = __shfl(acc, ln + 1), a2 = __shfl(acc, ln + 2);
        if (seg == 0) {
            const int row = b * L + i0 + wv;
            float s = sqrtf(acc + a1 + a2);
            if (g < P) nw[(size_t)row * P + g] = s;
            else       nrm[row] = s;
        }
    }
}

// ---------------------------------------------------------------- k_main
// 512 threads. bx<P: pair GEMM for p=bx. bx>=P: side tile.
__global__ __launch_bounds__(512) void
k_main(const float* __restrict__ cp, const float* __restrict__ ch,
       const u16* __restrict__ cpb, const u16* __restrict__ chb,
       const float* __restrict__ np_, const float* __restrict__ nh_,
       const float* __restrict__ nw1p, const float* __restrict__ nw1h,
       const int* __restrict__ mask_p, const int* __restrict__ mask_h,
       const float* __restrict__ w0, const float* __restrict__ w1,
       const float* __restrict__ w2, const float* __restrict__ w3,
       float* __restrict__ out)
{
    __shared__ __align__(16) char smem[SMEM_BYTES];
    const int bx = blockIdx.x, b = blockIdx.y, t = threadIdx.x;
    const int wv = t >> 6, ln = t & 63;
    float* out_p = out;
    float* out_h = out + (size_t)B * L * C;

    if (bx < P) {
        // ==================== pair path (round-16, unchanged) ====================
        const int p = bx;
        u16*  sB    = (u16*)smem;                      // [128][104]
        float* snwA = (float*)(smem + 26624);
        float* snwB = (float*)(smem + 27136);
        float* smA  = (float*)(smem + 27648);
        float* smB  = (float*)(smem + 28160);
        float* pJmax= (float*)(smem + 28672);
        float* pJsum= (float*)(smem + 29184);
        float* pImax= (float*)(smem + 29696);          // [8][128]
        float* pIsum= (float*)(smem + 33792);          // [8][128]
        float* sRed = (float*)(smem + 37888);          // 4

        if (t < 128) {
            snwA[t] = nw1p[(b * L + t) * P + p];
            snwB[t] = nw1h[(b * L + t) * P + p];
            smA[t] = (float)mask_p[b * L + t];
            smB[t] = (float)mask_h[b * L + t];
        }
        __syncthreads();

        if (t < 64) {
            float a0 = smB[t], a1 = smB[t + 64];
            float mx = fmaxf(a0, a1), sm = a0 + a1;
            for (int d = 1; d < 64; d <<= 1) {
                mx = fmaxf(mx, __shfl_xor(mx, d));
                sm += __shfl_xor(sm, d);
            }
            if (t == 0) { sRed[2] = mx; sRed[3] = sm; }
        } else if (t < 128) {
            const int l = t - 64;
            float a0 = smA[l], a1 = smA[l + 64];
            float mx = fmaxf(a0, a1), sm = a0 + a1;
            for (int d = 1; d < 64; d <<= 1) {
                mx = fmaxf(mx, __shfl_xor(mx, d));
                sm += __shfl_xor(sm, d);
            }
            if (l == 0) { sRed[0] = mx; sRed[1] = sm; }
        }

        {   // stage B (h-side bf16 rows), stride 104 u16: 128 rows x 13 uint4
            const uint4* src = (const uint4*)(chb + (size_t)b * L * 128);
            for (int idx = t; idx < 128 * 13; idx += 512) {
                int row = idx / 13, cc = idx - row * 13;
                uint4 v = src[row * 16 + cc];
                *(uint4*)&sB[row * 104 + cc * 8] = v;
            }
        }
        __syncthreads();

        const int m = ln & 15, q = ln >> 4;

        float swv[4][8];
        #pragma unroll
        for (int ks = 0; ks < 4; ++ks)
            #pragma unroll
            for (int e = 0; e < 8; ++e) {
                int k = ks * 32 + q * 8 + e;
                float w = (k < H) ? w1[p * H + k] : 0.f;
                swv[ks][e] = w * w;
            }

        f4 acc[8];
        #pragma unroll
        for (int ct = 0; ct < 8; ++ct) acc[ct] = (f4){0.f, 0.f, 0.f, 0.f};

        const uint4* gA = (const uint4*)(cpb + (size_t)(b * L + wv * 16 + m) * 128);

        #pragma unroll
        for (int ks = 0; ks < 4; ++ks) {
            uint4 va = gA[ks * 4 + q];
            sh8 af;
            {
                u32 vs[4] = {va.x, va.y, va.z, va.w};
                u32 r[4];
                #pragma unroll
                for (int e = 0; e < 4; ++e) {
                    float f0 = bf2f(vs[e] & 0xffffu) * swv[ks][2 * e];
                    float f1 = bf2f(vs[e] >> 16) * swv[ks][2 * e + 1];
                    r[e] = (u32)f2bf(f0) | ((u32)f2bf(f1) << 16);
                }
                uint4 o = {r[0], r[1], r[2], r[3]};
                af = __builtin_bit_cast(sh8, o);
            }
            const int ko = ks * 32 + q * 8;
            const bool oob = (ks == 3) && (q > 0);     // k>=104: af==0; bb would be garbage
            #pragma unroll
            for (int ct = 0; ct < 8; ++ct) {
                sh8 bb = oob ? zfrag() : *(const sh8*)&sB[(ct * 16 + m) * 104 + ko];
                acc[ct] = __builtin_amdgcn_mfma_f32_16x16x32_bf16(af, bb, acc[ct], 0, 0, 0);
            }
        }

        // Hoisted reciprocals (keeper). Masked rows have EXACT zero norms and
        // exact-zero acc; 1e-4 per-factor clamp == old 1e-8 product clamp.
        float rnB[8], mBv[8], imax[8], isum[8];
        #pragma unroll
        for (int ct = 0; ct < 8; ++ct) {
            const int j = ct * 16 + m;
            rnB[ct] = __builtin_amdgcn_rcpf(fmaxf(snwB[j], 1e-4f));
            mBv[ct] = smB[j];
            imax[ct] = MINV; isum[ct] = 0.f;
        }
        #pragma unroll
        for (int reg = 0; reg < 4; ++reg) {
            const int i = wv * 16 + q * 4 + reg;
            const float rna = __builtin_amdgcn_rcpf(fmaxf(snwA[i], 1e-4f));
            const float ma = smA[i];
            float jmax = MINV, jsum = 0.f;
            #pragma unroll
            for (int ct = 0; ct < 8; ++ct) {
                float v = acc[ct][reg] * (rna * rnB[ct]);
                jmax = fmaxf(jmax, mBv[ct] > 0.f ? v : MINV);
                jsum += mBv[ct] > 0.f ? v : 0.f;
                imax[ct] = fmaxf(imax[ct], ma > 0.f ? v : MINV);
                isum[ct] += ma > 0.f ? v : 0.f;
            }
            for (int d = 1; d < 16; d <<= 1) {
                jmax = fmaxf(jmax, __shfl_xor(jmax, d));
                jsum += __shfl_xor(jsum, d);
            }
            if (m == 0) { pJmax[i] = jmax; pJsum[i] = jsum; }
        }
        #pragma unroll
        for (int ct = 0; ct < 8; ++ct) {
            float mx = imax[ct], sm = isum[ct];
            mx = fmaxf(mx, __shfl_xor(mx, 16)); sm += __shfl_xor(sm, 16);
            mx = fmaxf(mx, __shfl_xor(mx, 32)); sm += __shfl_xor(sm, 32);
            if (q == 0) { const int j = ct * 16 + m; pImax[wv * 128 + j] = mx; pIsum[wv * 128 + j] = sm; }
        }
        __syncthreads();

        if (t < 128) {
            const int i = t;
            const float ma = smA[i];
            const float mm = ma * sRed[2];
            const float cnt = ma * sRed[3];
            float* orow = out_p + ((size_t)b * L + i) * C;
            orow[23 + p] = pJmax[i] * mm;
            orow[43 + p] = ma * pJsum[i] / fmaxf(cnt, EPSF);

            const float mb = smB[i];
            float hmax = MINV, hsum = 0.f;
            #pragma unroll
            for (int s = 0; s < 8; ++s) {
                hmax = fmaxf(hmax, pImax[s * 128 + i]);
                hsum += pIsum[s * 128 + i];
            }
            float* hrow = out_h + ((size_t)b * L + i) * C;
            hrow[23 + p] = hmax * mb * sRed[0];
            hrow[43 + p] = mb * hsum / fmaxf(mb * sRed[1], EPSF);
        }
    } else {
        // ==================== side path ====================
        // LDS map: BvI (jj-pair-interleaved compact B panel,
        // dword[(jj>>1)*104 + 2*kp + (jj&1)], <= 64 pairs) @0;
        // overlay 3a: Bcols [64][208B] @0 + w2sq [64][208B] @13312;
        // overlay post-3b: Dscr [8][64][9]f32 @0.
        // scosC f[8][128] @26624; sa f[8][100] @30720 (bank 0);
        // sam @33928 (bank 2); sax @37136 (bank 4); sl @40344 (bank 6);
        // overlay pre-phase2: snB@33928[128]f, snA@34440[8]f, cidx@34472;
        // pnv @40744.
        const int e = bx - P;
        const int side = e >> 4, tile = e & 15;
        const int i0 = tile * TI;
        const float* Bv  = side ? cp : ch;
        const float* A   = side ? ch : cp;
        const u16*  Ab16 = side ? chb : cpb;
        const u16*  Bvb  = side ? cpb : chb;
        const float* nA_ = side ? nh_ : np_;
        const float* nB_ = side ? np_ : nh_;
        const int* maskA = side ? mask_h : mask_p;
        const int* maskB = side ? mask_p : mask_h;
        float* outBase = out + ((size_t)side * B * L + (size_t)b * L) * C;

        float* scosC = (float*)(smem + 26624);
        float* sa    = (float*)(smem + 30720);
        float* sam   = (float*)(smem + 33928);   // +8 B: bank 2
        float* sax   = (float*)(smem + 37136);   // +16 B: bank 4
        float* sl    = (float*)(smem + 40344);   // +24 B: bank 6
        float* snB   = (float*)(smem + 33928);   // overlay in sam region
        float* snA   = (float*)(smem + 34440);
        u16*  cidx  = (u16*)(smem + 34472);
        int*   pnv   = (int*)(smem + 40744);

        // ---- phase 0: zero scosC; valid-j list (wave 0); sa staging (2-7)
        scosC[t] = 0.f;
        scosC[t + 512] = 0.f;
        if (wv == 0) {
            // init cidx first (same wave as the scatter below -> LDS ops
            // retire in program order; phase-cos indexes cidx[jj] for
            // jj >= nv to build global addresses).
            cidx[ln] = 0;
            cidx[64 + ln] = 0;
            int m0 = maskB[b * L + ln], m1 = maskB[b * L + 64 + ln];
            unsigned long long b0 = __ballot(m0 > 0);
            unsigned long long b1 = __ballot(m1 > 0);
            unsigned long long pre = (1ull << ln) - 1ull;
            int n0 = __popcll(b0);
            if (m0 > 0) cidx[__popcll(b0 & pre)] = (u16)ln;
            if (m1 > 0) cidx[n0 + __popcll(b1 & pre)] = (u16)(64 + ln);
            if (ln == 0) *pnv = n0 + __popcll(b1);
        } else if (wv >= 2) {
            for (int x = t - 128; x < TI * 128; x += 384) {
                int il = x >> 7, k = x & 127;
                if (k < H) sa[il * 100 + k] = A[((size_t)b * L + i0 + il) * H + k];
            }
        }
        __syncthreads();
        const int nv = *pnv;
        const int nct = (nv + 15) >> 4;

        // ---- phase 1: stage compact B panel jj-PAIR-INTERLEAVED:
        //      dword[(p2)*104 + 2*kp + (parity)]; one task = (pair p2, cc),
        //      reads two rows' uint4, writes 4x ds_write_b64. Odd tail row
        //      zeroed. Also norms + sl.
        {
            const uint4* src = (const uint4*)(Bvb + (size_t)b * L * 128);
            const int npair = (nv + 1) >> 1;
            for (int c = t; c < npair * 13; c += 512) {
                int p2 = c / 13, cc = c - p2 * 13;
                uint4 v0 = src[(int)cidx[2 * p2] * 16 + cc];
                uint4 v1;
                if (2 * p2 + 1 < nv) v1 = src[(int)cidx[2 * p2 + 1] * 16 + cc];
                else { v1.x = v1.y = v1.z = v1.w = 0u; }
                u32* dst = (u32*)smem + p2 * 104 + cc * 8;
                ((uint2*)dst)[0] = make_uint2(v0.x, v1.x);
                ((uint2*)dst)[1] = make_uint2(v0.y, v1.y);
                ((uint2*)dst)[2] = make_uint2(v0.z, v1.z);
                ((uint2*)dst)[3] = make_uint2(v0.w, v1.w);
            }
            if (t < 128) snB[t] = (t < nv) ? nB_[b * L + (int)cidx[t]] : 0.f;
            else if (t < 136) snA[t - 128] = nA_[b * L + i0 + (t - 136 + 8)];
            if (wv == 1) {
                int last = nv - 1; if (last < 0) last = 0;
                const float* lr = Bv + ((size_t)b * L + last) * H;
                sl[ln] = lr[ln];
                if (ln + 64 < H) sl[ln + 64] = lr[ln + 64];
            }
        }
        __syncthreads();

        // ---- phase cos: wave wv owns col-tile ct=wv (nct <= 8).
        //      B fragments straight from global chb/cpb (L2-resident,
        //      zero-padded to K=128 by k_prep). jj>=nv results masked to 0.
        const int m = ln & 15, q = ln >> 4;
        if (wv < nct) {
            const uint4* gA = (const uint4*)(Ab16 + (size_t)(b * L + i0 + (m & 7)) * 128);
            const int jj = wv * 16 + m;
            const int brow = (int)cidx[jj];            // 0 for jj>=nv (valid addr)
            const uint4* gB = (const uint4*)(Bvb + (size_t)(b * L + brow) * 128);
            f4 acc0 = (f4){0.f, 0.f, 0.f, 0.f};
            #pragma unroll
            for (int ks = 0; ks < 4; ++ks) {
                uint4 va = gA[ks * 4 + q];
                if (m >= 8) { va.x = va.y = va.z = va.w = 0u; }
                sh8 af = __builtin_bit_cast(sh8, va);   // zero for k>=100
                sh8 bb = __builtin_bit_cast(sh8, gB[ks * 4 + q]);
                acc0 = __builtin_amdgcn_mfma_f32_16x16x32_bf16(af, bb, acc0, 0, 0, 0);
            }
            if (q < 2) {
                #pragma unroll
                for (int reg = 0; reg < 4; ++reg) {
                    const int i = q * 4 + reg;
                    float val = acc0[reg] *
                        __builtin_amdgcn_rcpf(fmaxf(snA[i] * snB[jj], EPSF));
                    scosC[i * 128 + jj] = (jj < nv) ? val : 0.f;
                }
            }
        }
        __syncthreads();

        // ---- phase 2: butterfly scalars + attentive am/ax; wave wv = row wv.
        //      ALL-VECTOR pair loop: one ds_read_b64 gives the k-pair for two
        //      j's; one float2 ds_read_b64 broadcast gives two cos values.
        {
            const int il = wv;
            const int gi = i0 + il;
            const float mA = (float)maskA[b * L + gi];
            float c0 = scosC[il * 128 + ln], c1 = scosC[il * 128 + 64 + ln];
            float scj = c0 + c1;
            float mv0 = (ln < nv) ? c0 : MINV;
            float mv1 = (ln + 64 < nv) ? c1 : MINV;
            float cmx = fmaxf(mv0, mv1);
            for (int d = 1; d < 64; d <<= 1) {
                scj += __shfl_xor(scj, d);
                cmx = fmaxf(cmx, __shfl_xor(cmx, d));
            }
            const float mm = (nv > 0) ? mA : 0.f;
            if (ln == 0) {
                float* orow = outBase + (size_t)gi * C;
                orow[0] = cmx * mm;
                orow[1] = mA * scj / fmaxf(mA * (float)nv, EPSF);
            }
            if (ln < 50) {
                float am0 = 0.f, am1 = 0.f, ax0 = MINV, ax1 = MINV;
                const u32* bvi = (const u32*)smem + 2 * ln;      // kp = ln
                const float2* crp = (const float2*)(scosC + il * 128);
                const int npf = nv >> 1;                          // full pairs
                #pragma unroll 4
                for (int p2 = 0; p2 < npf; ++p2) {
                    uint2 pk = *(const uint2*)(bvi + p2 * 104);   // {j0,j1}@kp
                    float2 cj = crp[p2];                          // cos j0,j1
                    float v0a = cj.x * __uint_as_float(pk.x << 16);
                    float v1a = cj.x * __uint_as_float(pk.x & 0xffff0000u);
                    float v0b = cj.y * __uint_as_float(pk.y << 16);
                    float v1b = cj.y * __uint_as_float(pk.y & 0xffff0000u);
                    am0 += v0a + v0b; am1 += v1a + v1b;
                    ax0 = fmaxf(ax0, fmaxf(v0a, v0b));
                    ax1 = fmaxf(ax1, fmaxf(v1a, v1b));
                }
                if (nv & 1) {                                     // last lone j
                    u32 pkx = bvi[npf * 104];
                    float cjx = scosC[il * 128 + nv - 1];
                    float v0 = cjx * __uint_as_float(pkx << 16);
                    float v1 = cjx * __uint_as_float(pkx & 0xffff0000u);
                    am0 += v0; am1 += v1;
                    ax0 = fmaxf(ax0, v0); ax1 = fmaxf(ax1, v1);
                }
                const float rs = __builtin_amdgcn_rcpf(fmaxf(scj, EPSF));
                sam[il * 100 + 2 * ln] = am0 * rs; sam[il * 100 + 2 * ln + 1] = am1 * rs;
                sax[il * 100 + 2 * ln] = ax0 * mm; sax[il * 100 + 2 * ln + 1] = ax1 * mm;
            }
        }
        __syncthreads();

        // ---- phase 3a: Bcols (products, bf16, stride 104u16 @0) + w2sq
        //      (@13312); both zero-padded k in [100,104)
        for (int idx = t; idx < 64 * 13; idx += 512) {
            int row = idx / 13, cc = idx - row * 13;
            int kc = cc * 8;
            int il = row >> 3, col = row & 7;
            const float* sa_il  = sa  + il * 100;
            const float* sam_il = sam + il * 100;
            const float* sax_il = sax + il * 100;
            const float* p1 = (col >= 4) ? (col == 4 ? sl : col == 5 ? sam_il : sax_il)
                                         : sa_il;
            const float* p2 = (col == 0 || col == 4) ? sl :
                              (col == 1 || col == 5) ? sam_il :
                              (col == 2 || col == 6) ? sax_il : sa_il;
            u32 ow[4];
            #pragma unroll
            for (int e2 = 0; e2 < 4; ++e2) {
                int k0 = kc + 2 * e2;
                float f0 = (col < 7 && k0 < H)     ? p1[k0] * p2[k0]         : 0.f;
                float f1 = (col < 7 && k0 + 1 < H) ? p1[k0 + 1] * p2[k0 + 1] : 0.f;
                ow[e2] = pack2(f0, f1);
            }
            uint4 o = {ow[0], ow[1], ow[2], ow[3]};
            *(uint4*)(smem + row * 208 + kc * 2) = o;
        }
        for (int idx = t; idx < 64 * 13; idx += 512) {
            int kc = (idx % 13) * 8;
            int row = idx / 13;
            u32 ow[4];
            #pragma unroll
            for (int e2 = 0; e2 < 4; ++e2) {
                int k0 = kc + 2 * e2;
                float f0 = 0.f, f1 = 0.f;
                if (row < 60) {
                    const float* wr = (row < 20) ? w0 + row * H :
                                      (row < 40) ? w2 + (row - 20) * H :
                                                   w3 + (row - 40) * H;
                    if (k0 < H)     { float w = wr[k0];     f0 = w * w; }
                    if (k0 + 1 < H) { float w = wr[k0 + 1]; f1 = w * w; }
                } else if (row == 60) {
                    f0 = (k0 < H) ? 1.f : 0.f;
                    f1 = (k0 + 1 < H) ? 1.f : 0.f;
                }
                ow[e2] = pack2(f0, f1);
            }
            uint4 o = {ow[0], ow[1], ow[2], ow[3]};
            *(uint4*)(smem + 13312 + row * 208 + kc * 2) = o;
        }
        __syncthreads();

        // ---- phase 3b: D[61x7] = w2sq x Bcols^T per il (wave wv -> il=wv).
        //      ks==3,q>0 (k>=104): BOTH operands zeroed (OOB garbage).
        f4 d3[4];
        #pragma unroll
        for (int Mt = 0; Mt < 4; ++Mt) d3[Mt] = (f4){0.f, 0.f, 0.f, 0.f};
        {
            const int cn = m & 7;
            #pragma unroll
            for (int ks = 0; ks < 4; ++ks) {
                const int ko2 = (ks * 32 + q * 8) * 2;
                const bool oob = (ks == 3) && (q > 0);
                sh8 bb = oob ? zfrag()
                             : *(const sh8*)(smem + (wv * 8 + cn) * 208 + ko2);
                #pragma unroll
                for (int Mt = 0; Mt < 4; ++Mt) {
                    sh8 aa = oob ? zfrag()
                                 : *(const sh8*)(smem + 13312 + (Mt * 16 + m) * 208 + ko2);
                    d3[Mt] = __builtin_amdgcn_mfma_f32_16x16x32_bf16(aa, bb, d3[Mt], 0, 0, 0);
                }
            }
        }
        __syncthreads();   // all MFMA reads done before Dscr overwrites

        if (m < 8) {       // Dscr stride 9 dwords
            #pragma unroll
            for (int Mt = 0; Mt < 4; ++Mt)
                #pragma unroll
                for (int reg = 0; reg < 4; ++reg)
                    ((float*)smem)[wv * 576 + (Mt * 16 + q * 4 + reg) * 9 + m] = d3[Mt][reg];
        }
        __syncthreads();

        // ---- phase 3c: 504 output channels from Dscr
        for (int task = t; task < TI * 63; task += 512) {
            const int il = task / 63, c = task - il * 63;
            int row, dcol, nbcol, chn;
            if (c < 60) {
                const int grp = c / 20;
                row = c; dcol = grp; nbcol = 4 + grp;
                chn = ((grp == 0) ? 3 : (grp == 1) ? 64 : 85) + (c - grp * 20);
            } else {
                const int cc = c - 60;
                row = 60; dcol = cc; nbcol = 4 + cc;
                chn = (cc == 0) ? 2 : (cc == 1) ? 63 : 84;
            }
            const float* Dr = (const float*)smem + il * 576 + row * 9;
            float d = Dr[dcol], na = Dr[3], nb = Dr[nbcol];
            outBase[(size_t)(i0 + il) * C + chn] =
                d / (fmaxf(sqrtf(na), EPSF) * fmaxf(sqrtf(nb), EPSF));
        }
    }
}

// ---------------------------------------------------------------- launch
extern "C" void kernel_launch(void* const* d_in, const int* in_sizes, int n_in,
                              void* d_out, int out_size, void* d_ws, size_t ws_size,
                              hipStream_t stream)
{
    const float* ctx_p = (const float*)d_in[0];
    const int*   mask_p = (const int*)d_in[1];
    const float* ctx_h = (const float*)d_in[2];
    const int*   mask_h = (const int*)d_in[3];
    const float* w0 = (const float*)d_in[4];
    const float* w1 = (const float*)d_in[5];
    const float* w2 = (const float*)d_in[6];
    const float* w3 = (const float*)d_in[7];
    float* out = (float*)d_out;

    float* ws   = (float*)d_ws;
    float* cp   = ws;                       // B*L*H
    float* ch   = cp   + B * L * H;
    float* np_  = ch   + B * L * H;         // B*L
    float* nh_  = np_  + B * L;
    float* nw1p = nh_  + B * L;             // B*L*P
    float* nw1h = nw1p + B * L * P;
    u16*   cpb  = (u16*)(nw1h + B * L * P); // B*L*128 u16
    u16*   chb  = cpb + B * L * 128;

    k_prep<<<dim3(L / 8, B, 2), dim3(512), 0, stream>>>(
        ctx_p, mask_p, ctx_h, mask_h, w1,
        cp, ch, cpb, chb, np_, nh_, nw1p, nw1h);
    k_main<<<dim3(P + 32, B), dim3(512), 0, stream>>>(
        cp, ch, cpb, chb, np_, nh_, nw1p, nw1h, mask_p, mask_h,
        w0, w1, w2, w3, out);
}

// Round 4
// 116.952 us; speedup vs baseline: 1.0673x; 1.0673x over previous
//
#include <hip/hip_runtime.h>
#include <math.h>

// MatchingLayer (BiMPM-style) — MI355X. Round 18 = round-16 base (best:
// 49.0us k_main) + three provably-net-negative issue-count deltas:
//   * P2: cos pair read as float2 broadcast (64 -> 32 LDS broadcast ops/wave;
//     bp gather + panel layout UNTOUCHED — R15/R17's poisons avoided),
//   * w2sq table (w0^2/w2^2/w3^2/ones, bf16) precomputed ONCE in k_prep into
//     workspace; side blocks stage it via coalesced b128 copy instead of
//     recomputing (~500 VALU-inst + ~330 global loads per block saved),
//   * scosC zeroing via float2 stores.
// Keepers: sam/sax/sl bank stagger, pair-path hoisted reciprocals.
// Grid (20+32, B) x 512 thr. B=32, L=128, H=100, P=20, C=105.

namespace {
constexpr int B = 32;
constexpr int L = 128;
constexpr int H = 100;
constexpr int P = 20;
constexpr int C = 105;
constexpr int TI = 8;            // i-rows per side tile
constexpr int SMEM_BYTES = 40768;
constexpr float EPSF = 1e-8f;
constexpr float MINV = -1e7f;
}

typedef unsigned short u16;
typedef unsigned int u32;
typedef short sh8 __attribute__((ext_vector_type(8)));   // 8 bf16 (4 VGPRs)
typedef float f4 __attribute__((ext_vector_type(4)));

__device__ __forceinline__ u16 f2bf(float f) {           // RNE f32->bf16
    u32 u = __float_as_uint(f);
    u += 0x7FFFu + ((u >> 16) & 1u);
    return (u16)(u >> 16);
}
__device__ __forceinline__ float bf2f(u32 h) {
    return __uint_as_float(h << 16);
}
__device__ __forceinline__ u32 pack2(float a, float b) {
    return (u32)f2bf(a) | ((u32)f2bf(b) << 16);
}
__device__ __forceinline__ sh8 zfrag() {
    return __builtin_bit_cast(sh8, (uint4){0u, 0u, 0u, 0u});
}

// ---------------------------------------------------------------- k_prep
// grid (L/8, B, 2), block 512. Block = 8 rows. Phase A: masked vector
// (fp32 + bf16 K=128 pad) + v^2 into LDS. Phase B: wave w = row w, 21 norm
// tasks x 3-lane K-split. Block (0,0,0) additionally emits the w2sq table.
__global__ __launch_bounds__(512) void
k_prep(const float* __restrict__ ctx_p, const int* __restrict__ mask_p,
       const float* __restrict__ ctx_h, const int* __restrict__ mask_h,
       const float* __restrict__ w0, const float* __restrict__ w1,
       const float* __restrict__ w2, const float* __restrict__ w3,
       float* __restrict__ cp, float* __restrict__ ch,
       u16* __restrict__ cpb, u16* __restrict__ chb,
       float* __restrict__ np_, float* __restrict__ nh_,
       float* __restrict__ nwp, float* __restrict__ nwh,
       u16* __restrict__ w2sq_g)
{
    const int bx = blockIdx.x, b = blockIdx.y, side = blockIdx.z, t = threadIdx.x;
    const int i0 = bx * 8;
    const float* ctx = side ? ctx_h : ctx_p;
    const int*  mask = side ? mask_h : mask_p;
    float* dst  = side ? ch  : cp;
    u16*   dstb = side ? chb : cpb;
    float* nrm  = side ? nh_ : np_;
    float* nw   = side ? nwh : nwp;

    __shared__ __align__(16) float sv2[8][112];

    #pragma unroll
    for (int it = 0; it < 2; ++it) {
        int idx = it * 512 + t;
        int rr = idx >> 7, k = idx & 127;
        const int row = b * L + i0 + rr;
        const float m = (float)mask[row];
        float v = 0.f;
        if (k < H) {
            v = ctx[(size_t)row * H + k] * m;
            dst[(size_t)row * H + k] = v;
            sv2[rr][k] = v * v;
        }
        dstb[(size_t)row * 128 + k] = f2bf(v);
    }

    // w2sq table: 64 rows x 104 u16 (bf16 of squared weights), rows 0..19 =
    // w0^2, 20..39 = w2^2, 40..59 = w3^2, 60 = ones(k<H), 61..63 = 0.
    // Computed once by block (0,0,0) — identical for all k_main side blocks.
    if (bx == 0 && b == 0 && side == 0) {
        for (int idx = t; idx < 64 * 13; idx += 512) {
            int kc = (idx % 13) * 8;
            int row = idx / 13;
            u32 ow[4];
            #pragma unroll
            for (int e2 = 0; e2 < 4; ++e2) {
                int k0 = kc + 2 * e2;
                float f0 = 0.f, f1 = 0.f;
                if (row < 60) {
                    const float* wr = (row < 20) ? w0 + row * H :
                                      (row < 40) ? w2 + (row - 20) * H :
                                                   w3 + (row - 40) * H;
                    if (k0 < H)     { float w = wr[k0];     f0 = w * w; }
                    if (k0 + 1 < H) { float w = wr[k0 + 1]; f1 = w * w; }
                } else if (row == 60) {
                    f0 = (k0 < H) ? 1.f : 0.f;
                    f1 = (k0 + 1 < H) ? 1.f : 0.f;
                }
                ow[e2] = pack2(f0, f1);
            }
            uint4 o = {ow[0], ow[1], ow[2], ow[3]};
            *(uint4*)(w2sq_g + row * 104 + kc) = o;
        }
    }
    __syncthreads();

    const int wv = t >> 6, ln = t & 63;
    if (ln < 63) {
        const int g = ln / 3, seg = ln - 3 * g;
        const int k0 = (seg == 0) ? 0 : (seg == 1) ? 8 : 16;
        const int k1 = (seg == 0) ? 8 : (seg == 1) ? 16 : 25;
        const float4* v4 = (const float4*)sv2[wv];
        float acc = 0.f;
        if (g < P) {
            const float4* w4 = (const float4*)(w1 + g * H);
            for (int k = k0; k < k1; ++k) {
                float4 w = w4[k], s = v4[k];
                acc += w.x * w.x * s.x + w.y * w.y * s.y +
                       w.z * w.z * s.z + w.w * w.w * s.w;
            }
        } else {
            for (int k = k0; k < k1; ++k) {
                float4 s = v4[k];
                acc += s.x + s.y + s.z + s.w;
            }
        }
        float a1 = __shfl(acc, ln + 1), a2 = __shfl(acc, ln + 2);
        if (seg == 0) {
            const int row = b * L + i0 + wv;
            float s = sqrtf(acc + a1 + a2);
            if (g < P) nw[(size_t)row * P + g] = s;
            else       nrm[row] = s;
        }
    }
}

// ---------------------------------------------------------------- k_main
// 512 threads. bx<P: pair GEMM for p=bx. bx>=P: side tile.
// LDS B-tiles use stride 104 u16 (208 B). For ks==3 && q>0 (k>=104) the
// B fragment is explicitly zeroed (0 x Inf/NaN = NaN — never multiply
// against OOB garbage).
__global__ __launch_bounds__(512) void
k_main(const float* __restrict__ cp, const float* __restrict__ ch,
       const u16* __restrict__ cpb, const u16* __restrict__ chb,
       const float* __restrict__ np_, const float* __restrict__ nh_,
       const float* __restrict__ nw1p, const float* __restrict__ nw1h,
       const int* __restrict__ mask_p, const int* __restrict__ mask_h,
       const float* __restrict__ w0, const float* __restrict__ w1,
       const float* __restrict__ w2, const float* __restrict__ w3,
       const u16* __restrict__ w2sq_g,
       float* __restrict__ out)
{
    __shared__ __align__(16) char smem[SMEM_BYTES];
    const int bx = blockIdx.x, b = blockIdx.y, t = threadIdx.x;
    const int wv = t >> 6, ln = t & 63;
    float* out_p = out;
    float* out_h = out + (size_t)B * L * C;

    if (bx < P) {
        // ==================== pair path (round-16, unchanged) ====================
        const int p = bx;
        u16*  sB    = (u16*)smem;                      // [128][104]
        float* snwA = (float*)(smem + 26624);
        float* snwB = (float*)(smem + 27136);
        float* smA  = (float*)(smem + 27648);
        float* smB  = (float*)(smem + 28160);
        float* pJmax= (float*)(smem + 28672);
        float* pJsum= (float*)(smem + 29184);
        float* pImax= (float*)(smem + 29696);          // [8][128]
        float* pIsum= (float*)(smem + 33792);          // [8][128]
        float* sRed = (float*)(smem + 37888);          // 4

        if (t < 128) {
            snwA[t] = nw1p[(b * L + t) * P + p];
            snwB[t] = nw1h[(b * L + t) * P + p];
            smA[t] = (float)mask_p[b * L + t];
            smB[t] = (float)mask_h[b * L + t];
        }
        __syncthreads();

        if (t < 64) {
            float a0 = smB[t], a1 = smB[t + 64];
            float mx = fmaxf(a0, a1), sm = a0 + a1;
            for (int d = 1; d < 64; d <<= 1) {
                mx = fmaxf(mx, __shfl_xor(mx, d));
                sm += __shfl_xor(sm, d);
            }
            if (t == 0) { sRed[2] = mx; sRed[3] = sm; }
        } else if (t < 128) {
            const int l = t - 64;
            float a0 = smA[l], a1 = smA[l + 64];
            float mx = fmaxf(a0, a1), sm = a0 + a1;
            for (int d = 1; d < 64; d <<= 1) {
                mx = fmaxf(mx, __shfl_xor(mx, d));
                sm += __shfl_xor(sm, d);
            }
            if (l == 0) { sRed[0] = mx; sRed[1] = sm; }
        }

        {   // stage B (h-side bf16 rows), stride 104 u16: 128 rows x 13 uint4
            const uint4* src = (const uint4*)(chb + (size_t)b * L * 128);
            for (int idx = t; idx < 128 * 13; idx += 512) {
                int row = idx / 13, cc = idx - row * 13;
                uint4 v = src[row * 16 + cc];
                *(uint4*)&sB[row * 104 + cc * 8] = v;
            }
        }
        __syncthreads();

        const int m = ln & 15, q = ln >> 4;

        float swv[4][8];
        #pragma unroll
        for (int ks = 0; ks < 4; ++ks)
            #pragma unroll
            for (int e = 0; e < 8; ++e) {
                int k = ks * 32 + q * 8 + e;
                float w = (k < H) ? w1[p * H + k] : 0.f;
                swv[ks][e] = w * w;
            }

        f4 acc[8];
        #pragma unroll
        for (int ct = 0; ct < 8; ++ct) acc[ct] = (f4){0.f, 0.f, 0.f, 0.f};

        const uint4* gA = (const uint4*)(cpb + (size_t)(b * L + wv * 16 + m) * 128);

        #pragma unroll
        for (int ks = 0; ks < 4; ++ks) {
            uint4 va = gA[ks * 4 + q];
            sh8 af;
            {
                u32 vs[4] = {va.x, va.y, va.z, va.w};
                u32 r[4];
                #pragma unroll
                for (int e = 0; e < 4; ++e) {
                    float f0 = bf2f(vs[e] & 0xffffu) * swv[ks][2 * e];
                    float f1 = bf2f(vs[e] >> 16) * swv[ks][2 * e + 1];
                    r[e] = (u32)f2bf(f0) | ((u32)f2bf(f1) << 16);
                }
                uint4 o = {r[0], r[1], r[2], r[3]};
                af = __builtin_bit_cast(sh8, o);
            }
            const int ko = ks * 32 + q * 8;
            const bool oob = (ks == 3) && (q > 0);     // k>=104: af==0; bb would be garbage
            #pragma unroll
            for (int ct = 0; ct < 8; ++ct) {
                sh8 bb = oob ? zfrag() : *(const sh8*)&sB[(ct * 16 + m) * 104 + ko];
                acc[ct] = __builtin_amdgcn_mfma_f32_16x16x32_bf16(af, bb, acc[ct], 0, 0, 0);
            }
        }

        // Hoisted reciprocals (keeper). Masked rows have EXACT zero norms and
        // exact-zero acc; 1e-4 per-factor clamp == old 1e-8 product clamp.
        float rnB[8], mBv[8], imax[8], isum[8];
        #pragma unroll
        for (int ct = 0; ct < 8; ++ct) {
            const int j = ct * 16 + m;
            rnB[ct] = __builtin_amdgcn_rcpf(fmaxf(snwB[j], 1e-4f));
            mBv[ct] = smB[j];
            imax[ct] = MINV; isum[ct] = 0.f;
        }
        #pragma unroll
        for (int reg = 0; reg < 4; ++reg) {
            const int i = wv * 16 + q * 4 + reg;
            const float rna = __builtin_amdgcn_rcpf(fmaxf(snwA[i], 1e-4f));
            const float ma = smA[i];
            float jmax = MINV, jsum = 0.f;
            #pragma unroll
            for (int ct = 0; ct < 8; ++ct) {
                float v = acc[ct][reg] * (rna * rnB[ct]);
                jmax = fmaxf(jmax, mBv[ct] > 0.f ? v : MINV);
                jsum += mBv[ct] > 0.f ? v : 0.f;
                imax[ct] = fmaxf(imax[ct], ma > 0.f ? v : MINV);
                isum[ct] += ma > 0.f ? v : 0.f;
            }
            for (int d = 1; d < 16; d <<= 1) {
                jmax = fmaxf(jmax, __shfl_xor(jmax, d));
                jsum += __shfl_xor(jsum, d);
            }
            if (m == 0) { pJmax[i] = jmax; pJsum[i] = jsum; }
        }
        #pragma unroll
        for (int ct = 0; ct < 8; ++ct) {
            float mx = imax[ct], sm = isum[ct];
            mx = fmaxf(mx, __shfl_xor(mx, 16)); sm += __shfl_xor(sm, 16);
            mx = fmaxf(mx, __shfl_xor(mx, 32)); sm += __shfl_xor(sm, 32);
            if (q == 0) { const int j = ct * 16 + m; pImax[wv * 128 + j] = mx; pIsum[wv * 128 + j] = sm; }
        }
        __syncthreads();

        if (t < 128) {
            const int i = t;
            const float ma = smA[i];
            const float mm = ma * sRed[2];
            const float cnt = ma * sRed[3];
            float* orow = out_p + ((size_t)b * L + i) * C;
            orow[23 + p] = pJmax[i] * mm;
            orow[43 + p] = ma * pJsum[i] / fmaxf(cnt, EPSF);

            const float mb = smB[i];
            float hmax = MINV, hsum = 0.f;
            #pragma unroll
            for (int s = 0; s < 8; ++s) {
                hmax = fmaxf(hmax, pImax[s * 128 + i]);
                hsum += pIsum[s * 128 + i];
            }
            float* hrow = out_h + ((size_t)b * L + i) * C;
            hrow[23 + p] = hmax * mb * sRed[0];
            hrow[43 + p] = mb * hsum / fmaxf(mb * sRed[1], EPSF);
        }
    } else {
        // ==================== side path ====================
        // LDS map: BvC [<=128][208B] @0; overlay 3a: Bcols [64][208B] @0 +
        // w2sq [64][208B] @13312; overlay post-3b: Dscr [8][64][9]f32 @0.
        // scosC f[8][128] @26624; sa f[8][100] @30720 (bank 0);
        // sam @33928 (bank 2); sax @37136 (bank 4); sl @40344 (bank 6);
        // overlay pre-phase2: snB@33928[128]f, snA@34440[8]f, cidx@34472;
        // pnv @40744.
        const int e = bx - P;
        const int side = e >> 4, tile = e & 15;
        const int i0 = tile * TI;
        const float* Bv  = side ? cp : ch;
        const float* A   = side ? ch : cp;
        const u16*  Ab16 = side ? chb : cpb;
        const u16*  Bvb  = side ? cpb : chb;
        const float* nA_ = side ? nh_ : np_;
        const float* nB_ = side ? np_ : nh_;
        const int* maskA = side ? mask_h : mask_p;
        const int* maskB = side ? mask_p : mask_h;
        float* outBase = out + ((size_t)side * B * L + (size_t)b * L) * C;

        float* scosC = (float*)(smem + 26624);
        float* sa    = (float*)(smem + 30720);
        float* sam   = (float*)(smem + 33928);   // +8 B: bank 2
        float* sax   = (float*)(smem + 37136);   // +16 B: bank 4
        float* sl    = (float*)(smem + 40344);   // +24 B: bank 6
        float* snB   = (float*)(smem + 33928);   // overlay in sam region
        float* snA   = (float*)(smem + 34440);
        u16*  cidx  = (u16*)(smem + 34472);
        int*   pnv   = (int*)(smem + 40744);

        // ---- phase 0: zero scosC (float2); valid-j list (wave 0);
        //      sa staging (waves 2-7)
        *(float2*)(scosC + 2 * t) = make_float2(0.f, 0.f);
        if (wv == 0) {
            int m0 = maskB[b * L + ln], m1 = maskB[b * L + 64 + ln];
            unsigned long long b0 = __ballot(m0 > 0);
            unsigned long long b1 = __ballot(m1 > 0);
            unsigned long long pre = (1ull << ln) - 1ull;
            int n0 = __popcll(b0);
            if (m0 > 0) cidx[__popcll(b0 & pre)] = (u16)ln;
            if (m1 > 0) cidx[n0 + __popcll(b1 & pre)] = (u16)(64 + ln);
            if (ln == 0) *pnv = n0 + __popcll(b1);
        } else if (wv >= 2) {
            for (int x = t - 128; x < TI * 128; x += 384) {
                int il = x >> 7, k = x & 127;
                if (k < H) sa[il * 100 + k] = A[((size_t)b * L + i0 + il) * H + k];
            }
        }
        __syncthreads();
        const int nv = *pnv;
        const int nct = (nv + 15) >> 4;

        // ---- phase 1: compact bf16 Bv rows (stride 208 B, zero tail) +
        //      norms + sl
        {
            const uint4* src = (const uint4*)(Bvb + (size_t)b * L * 128);
            for (int c = t; c < nct * 208; c += 512) {   // rows x 13 uint4
                int jj = c / 13, cc = c - jj * 13;
                uint4 v;
                if (jj < nv) v = src[(int)cidx[jj] * 16 + cc];
                else { v.x = v.y = v.z = v.w = 0u; }
                *(uint4*)(smem + jj * 208 + cc * 16) = v;
            }
            if (t < 128) snB[t] = (t < nv) ? nB_[b * L + (int)cidx[t]] : 0.f;
            else if (t < 136) snA[t - 128] = nA_[b * L + i0 + (t - 128)];
            if (wv == 1) {
                int last = nv - 1; if (last < 0) last = 0;
                const float* lr = Bv + ((size_t)b * L + last) * H;
                sl[ln] = lr[ln];
                if (ln + 64 < H) sl[ln + 64] = lr[ln + 64];
            }
        }
        __syncthreads();

        // ---- phase cos: wave wv owns col-tile ct=wv (nct <= 8)
        const int m = ln & 15, q = ln >> 4;
        if (wv < nct) {
            const uint4* gA = (const uint4*)(Ab16 + (size_t)(b * L + i0 + (m & 7)) * 128);
            f4 acc0 = (f4){0.f, 0.f, 0.f, 0.f};
            #pragma unroll
            for (int ks = 0; ks < 4; ++ks) {
                uint4 va = gA[ks * 4 + q];
                if (m >= 8) { va.x = va.y = va.z = va.w = 0u; }
                sh8 af = __builtin_bit_cast(sh8, va);   // zero for k>=100
                const int ko2 = (ks * 32 + q * 8) * 2;
                const bool oob = (ks == 3) && (q > 0);
                sh8 bb = oob ? zfrag()
                             : *(const sh8*)(smem + (wv * 16 + m) * 208 + ko2);
                acc0 = __builtin_amdgcn_mfma_f32_16x16x32_bf16(af, bb, acc0, 0, 0, 0);
            }
            if (q < 2) {
                #pragma unroll
                for (int reg = 0; reg < 4; ++reg) {
                    const int i = q * 4 + reg;
                    const int jj = wv * 16 + m;
                    scosC[i * 128 + jj] = acc0[reg] *
                        __builtin_amdgcn_rcpf(fmaxf(snA[i] * snB[jj], EPSF));
                }
            }
        }
        __syncthreads();

        // ---- phase 2: butterfly scalars + attentive am/ax; wave wv = row wv.
        //      cos pairs via float2 broadcast (half the broadcast ops); bp
        //      gather from the ROW-MAJOR panel, unchanged.
        {
            const int il = wv;
            const int gi = i0 + il;
            const float mA = (float)maskA[b * L + gi];
            float c0 = scosC[il * 128 + ln], c1 = scosC[il * 128 + 64 + ln];
            float scj = c0 + c1;
            float mv0 = (ln < nv) ? c0 : MINV;
            float mv1 = (ln + 64 < nv) ? c1 : MINV;
            float cmx = fmaxf(mv0, mv1);
            for (int d = 1; d < 64; d <<= 1) {
                scj += __shfl_xor(scj, d);
                cmx = fmaxf(cmx, __shfl_xor(cmx, d));
            }
            const float mm = (nv > 0) ? mA : 0.f;
            if (ln == 0) {
                float* orow = outBase + (size_t)gi * C;
                orow[0] = cmx * mm;
                orow[1] = mA * scj / fmaxf(mA * (float)nv, EPSF);
            }
            if (ln < 50) {
                float am0 = 0.f, am1 = 0.f, ax0 = MINV, ax1 = MINV;
                const u32* bp = (const u32*)smem + ln;   // row stride 52 dwords
                const float2* crp = (const float2*)(scosC + il * 128);
                const int npf = nv >> 1;
                #pragma unroll 4
                for (int p2 = 0; p2 < npf; ++p2) {
                    float2 cj = crp[p2];                 // broadcast b64
                    u32 pka = bp[(2 * p2) * 52];
                    u32 pkb = bp[(2 * p2 + 1) * 52];
                    float v0a = cj.x * __uint_as_float(pka << 16);
                    float v1a = cj.x * __uint_as_float(pka & 0xffff0000u);
                    float v0b = cj.y * __uint_as_float(pkb << 16);
                    float v1b = cj.y * __uint_as_float(pkb & 0xffff0000u);
                    am0 += v0a + v0b; am1 += v1a + v1b;
                    ax0 = fmaxf(ax0, fmaxf(v0a, v0b));   // max3-fusable
                    ax1 = fmaxf(ax1, fmaxf(v1a, v1b));
                }
                if (nv & 1) {                            // lone last j
                    u32 pk = bp[(nv - 1) * 52];
                    float cj = scosC[il * 128 + nv - 1];
                    float v0 = cj * __uint_as_float(pk << 16);
                    float v1 = cj * __uint_as_float(pk & 0xffff0000u);
                    am0 += v0; am1 += v1;
                    ax0 = fmaxf(ax0, v0); ax1 = fmaxf(ax1, v1);
                }
                const float rs = __builtin_amdgcn_rcpf(fmaxf(scj, EPSF));
                sam[il * 100 + 2 * ln] = am0 * rs; sam[il * 100 + 2 * ln + 1] = am1 * rs;
                sax[il * 100 + 2 * ln] = ax0 * mm; sax[il * 100 + 2 * ln + 1] = ax1 * mm;
            }
        }
        __syncthreads();

        // ---- phase 3a: Bcols (products, bf16, stride 104u16 @0) computed;
        //      w2sq (@13312) STAGED from the precomputed global table.
        for (int idx = t; idx < 64 * 13; idx += 512) {
            int row = idx / 13, cc = idx - row * 13;
            int kc = cc * 8;
            int il = row >> 3, col = row & 7;
            const float* sa_il  = sa  + il * 100;
            const float* sam_il = sam + il * 100;
            const float* sax_il = sax + il * 100;
            const float* p1 = (col >= 4) ? (col == 4 ? sl : col == 5 ? sam_il : sax_il)
                                         : sa_il;
            const float* p2 = (col == 0 || col == 4) ? sl :
                              (col == 1 || col == 5) ? sam_il :
                              (col == 2 || col == 6) ? sax_il : sa_il;
            u32 ow[4];
            #pragma unroll
            for (int e2 = 0; e2 < 4; ++e2) {
                int k0 = kc + 2 * e2;
                float f0 = (col < 7 && k0 < H)     ? p1[k0] * p2[k0]         : 0.f;
                float f1 = (col < 7 && k0 + 1 < H) ? p1[k0 + 1] * p2[k0 + 1] : 0.f;
                ow[e2] = pack2(f0, f1);
            }
            uint4 o = {ow[0], ow[1], ow[2], ow[3]};
            *(uint4*)(smem + row * 208 + kc * 2) = o;
        }
        {
            const uint4* wsrc = (const uint4*)w2sq_g;    // [64][13] uint4
            for (int idx = t; idx < 64 * 13; idx += 512) {
                int row = idx / 13, cc = idx - row * 13;
                *(uint4*)(smem + 13312 + row * 208 + cc * 16) = wsrc[idx];
            }
        }
        __syncthreads();

        // ---- phase 3b: D[61x7] = w2sq x Bcols^T per il (wave wv -> il=wv).
        //      ks==3,q>0 (k>=104): BOTH operands zeroed (OOB garbage).
        f4 d3[4];
        #pragma unroll
        for (int Mt = 0; Mt < 4; ++Mt) d3[Mt] = (f4){0.f, 0.f, 0.f, 0.f};
        {
            const int cn = m & 7;
            #pragma unroll
            for (int ks = 0; ks < 4; ++ks) {
                const int ko2 = (ks * 32 + q * 8) * 2;
                const bool oob = (ks == 3) && (q > 0);
                sh8 bb = oob ? zfrag()
                             : *(const sh8*)(smem + (wv * 8 + cn) * 208 + ko2);
                #pragma unroll
                for (int Mt = 0; Mt < 4; ++Mt) {
                    sh8 aa = oob ? zfrag()
                                 : *(const sh8*)(smem + 13312 + (Mt * 16 + m) * 208 + ko2);
                    d3[Mt] = __builtin_amdgcn_mfma_f32_16x16x32_bf16(aa, bb, d3[Mt], 0, 0, 0);
                }
            }
        }
        __syncthreads();   // all MFMA reads done before Dscr overwrites

        if (m < 8) {       // Dscr stride 9 dwords
            #pragma unroll
            for (int Mt = 0; Mt < 4; ++Mt)
                #pragma unroll
                for (int reg = 0; reg < 4; ++reg)
                    ((float*)smem)[wv * 576 + (Mt * 16 + q * 4 + reg) * 9 + m] = d3[Mt][reg];
        }
        __syncthreads();

        // ---- phase 3c: 504 output channels from Dscr
        for (int task = t; task < TI * 63; task += 512) {
            const int il = task / 63, c = task - il * 63;
            int row, dcol, nbcol, chn;
            if (c < 60) {
                const int grp = c / 20;
                row = c; dcol = grp; nbcol = 4 + grp;
                chn = ((grp == 0) ? 3 : (grp == 1) ? 64 : 85) + (c - grp * 20);
            } else {
                const int cc = c - 60;
                row = 60; dcol = cc; nbcol = 4 + cc;
                chn = (cc == 0) ? 2 : (cc == 1) ? 63 : 84;
            }
            const float* Dr = (const float*)smem + il * 576 + row * 9;
            float d = Dr[dcol], na = Dr[3], nb = Dr[nbcol];
            outBase[(size_t)(i0 + il) * C + chn] =
                d / (fmaxf(sqrtf(na), EPSF) * fmaxf(sqrtf(nb), EPSF));
        }
    }
}

// ---------------------------------------------------------------- launch
extern "C" void kernel_launch(void* const* d_in, const int* in_sizes, int n_in,
                              void* d_out, int out_size, void* d_ws, size_t ws_size,
                              hipStream_t stream)
{
    const float* ctx_p = (const float*)d_in[0];
    const int*   mask_p = (const int*)d_in[1];
    const float* ctx_h = (const float*)d_in[2];
    const int*   mask_h = (const int*)d_in[3];
    const float* w0 = (const float*)d_in[4];
    const float* w1 = (const float*)d_in[5];
    const float* w2 = (const float*)d_in[6];
    const float* w3 = (const float*)d_in[7];
    float* out = (float*)d_out;

    float* ws   = (float*)d_ws;
    float* cp   = ws;                       // B*L*H
    float* ch   = cp   + B * L * H;
    float* np_  = ch   + B * L * H;         // B*L
    float* nh_  = np_  + B * L;
    float* nw1p = nh_  + B * L;             // B*L*P
    float* nw1h = nw1p + B * L * P;
    u16*   cpb  = (u16*)(nw1h + B * L * P); // B*L*128 u16
    u16*   chb  = cpb + B * L * 128;
    u16*   w2sq = chb + B * L * 128;        // 64*104 u16

    k_prep<<<dim3(L / 8, B, 2), dim3(512), 0, stream>>>(
        ctx_p, mask_p, ctx_h, mask_h, w0, w1, w2, w3,
        cp, ch, cpb, chb, np_, nh_, nw1p, nw1h, w2sq);
    k_main<<<dim3(P + 32, B), dim3(512), 0, stream>>>(
        cp, ch, cpb, chb, np_, nh_, nw1p, nw1h, mask_p, mask_h,
        w0, w1, w2, w3, w2sq, out);
}